// Round 12
// baseline (208.616 us; speedup 1.0000x reference)
//
#include <hip/hip_runtime.h>
#include <hip/hip_bf16.h>
#include <stdint.h>

typedef __hip_bfloat16 bf16;
typedef __attribute__((ext_vector_type(8))) short bf16x8;
typedef __attribute__((ext_vector_type(4))) float f32x4;
typedef __attribute__((ext_vector_type(16))) float f32x16;
typedef __attribute__((ext_vector_type(4))) int i32x4;
typedef __attribute__((ext_vector_type(2))) int i32x2;

#define B_   2
#define S_   2048
#define HID_ 2048
#define H_   32
#define KV_  8
#define D_   64
#define KVD_ (KV_ * D_)
#define NT_  (S_ / 64)
#define LOG2E 1.4426950408889634f

__device__ __forceinline__ void gload_lds16(const void* g, void* l) {
  __builtin_amdgcn_global_load_lds(
      (const __attribute__((address_space(1))) uint32_t*)g,
      (__attribute__((address_space(3))) uint32_t*)l, 16, 0, 0);
}
__device__ __forceinline__ float fexp2(float x) { return __builtin_amdgcn_exp2f(x); }

__device__ __forceinline__ uint32_t cvtpk_bf16(float lo, float hi) {
  uint32_t r;
  asm("v_cvt_pk_bf16_f32 %0, %1, %2" : "=v"(r) : "v"(lo), "v"(hi));
  return r;
}
__device__ __forceinline__ void plane32_swap(uint32_t& a, uint32_t& b) {
  i32x2 r = __builtin_amdgcn_permlane32_swap((int)a, (int)b, false, false);
  a = (uint32_t)r[0]; b = (uint32_t)r[1];
}

// ---- fused f32 -> bf16 conversion over 5 buffers (one launch) ----
struct CvtJob { const float* s; bf16* d; int n4; };
__global__ __launch_bounds__(256) void cvt_multi(
    CvtJob j0, CvtJob j1, CvtJob j2, CvtJob j3, CvtJob j4) {
  CvtJob j;
  switch (blockIdx.y) {
    case 0: j = j0; break;
    case 1: j = j1; break;
    case 2: j = j2; break;
    case 3: j = j3; break;
    default: j = j4; break;
  }
  int i = blockIdx.x * blockDim.x + threadIdx.x;
  const int stride = gridDim.x * blockDim.x;
  for (; i < j.n4; i += stride) {
    float4 v = ((const float4*)j.s)[i];
    bf16 t[4];
    t[0] = __float2bfloat16(v.x);
    t[1] = __float2bfloat16(v.y);
    t[2] = __float2bfloat16(v.z);
    t[3] = __float2bfloat16(v.w);
    *reinterpret_cast<uint64_t*>(j.d + 4 * (size_t)i) = *reinterpret_cast<uint64_t*>(t);
  }
}

// ---------------- fused QKV projection ----------------
// Q (scaled by 0.125*log2e) -> row-major [B*S, HID].
// K -> row-major [B*S, KVD]. V -> transposed [B,KV,D,S].
__global__ __launch_bounds__(256, 3) void gemm_qkv(
    const bf16* __restrict__ A,
    const bf16* __restrict__ Wqp, const bf16* __restrict__ Wkp, const bf16* __restrict__ Wvp,
    const float* __restrict__ bqp, const float* __restrict__ bkp, const float* __restrict__ bvp,
    bf16* __restrict__ Cq, bf16* __restrict__ Ck, bf16* __restrict__ Cv) {
  const int lid0 = blockIdx.y * gridDim.x + blockIdx.x;
  const int q8 = (int)(gridDim.x * gridDim.y) >> 3;
  const int lid = (lid0 & 7) * q8 + (lid0 >> 3);
  const int bm = lid & 31;        // gridDim.x == 32
  const int bn_all = lid >> 5;

  const bf16* W; const float* bias; int bn;
  if (bn_all < 16)      { W = Wqp; bias = bqp; bn = bn_all; }
  else if (bn_all < 20) { W = Wkp; bias = bkp; bn = bn_all - 16; }
  else                  { W = Wvp; bias = bvp; bn = bn_all - 20; }
  const float oscale = (bn_all < 16) ? (0.125f * LOG2E) : 1.0f;

  __shared__ __align__(16) bf16 As[128 * 64];
  __shared__ __align__(16) bf16 Bs[128 * 64];
  const int tid = threadIdx.x;
  const int lane = tid & 63, wid = tid >> 6;
  const int wr = wid >> 1, wc = wid & 1;
  const int K = HID_;

  f32x4 acc[4][4] = {};

  for (int k0 = 0; k0 < K; k0 += 64) {
    __syncthreads();
#pragma unroll
    for (int c = 0; c < 4; ++c) {
      const int r = c * 32 + wid * 8 + (lane >> 3);
      const int gcolb = ((lane & 7) * 16) ^ ((r & 7) << 4);
      gload_lds16(A + (size_t)(bm * 128 + r) * K + k0 + (gcolb >> 1),
                  &As[(c * 32 + wid * 8) * 64]);
      gload_lds16(W + (size_t)(bn * 128 + r) * K + k0 + (gcolb >> 1),
                  &Bs[(c * 32 + wid * 8) * 64]);
    }
    __syncthreads();
#pragma unroll
    for (int ks = 0; ks < 2; ++ks) {
      bf16x8 af[4], bfr[4];
#pragma unroll
      for (int i = 0; i < 4; ++i) {
        const int ra = wr * 64 + i * 16 + (lane & 15);
        const int ka = (ks * 64 + ((lane >> 4) << 4)) ^ ((ra & 7) << 4);
        af[i] = *(const bf16x8*)((const char*)As + ra * 128 + ka);
        const int rb = wc * 64 + i * 16 + (lane & 15);
        const int kb = (ks * 64 + ((lane >> 4) << 4)) ^ ((rb & 7) << 4);
        bfr[i] = *(const bf16x8*)((const char*)Bs + rb * 128 + kb);
      }
      __builtin_amdgcn_s_setprio(1);
#pragma unroll
      for (int i = 0; i < 4; ++i)
#pragma unroll
        for (int j = 0; j < 4; ++j)
          acc[i][j] = __builtin_amdgcn_mfma_f32_16x16x32_bf16(af[i], bfr[j], acc[i][j], 0, 0, 0);
      __builtin_amdgcn_s_setprio(0);
    }
  }

  if (bn_all < 16) {
#pragma unroll
    for (int j = 0; j < 4; ++j) {
      const int n = bn * 128 + wc * 64 + j * 16 + (lane & 15);
      const float bv = bias[n];
#pragma unroll
      for (int i = 0; i < 4; ++i) {
        const int mb = bm * 128 + wr * 64 + i * 16 + ((lane >> 4) << 2);
#pragma unroll
        for (int e = 0; e < 4; ++e)
          Cq[(size_t)(mb + e) * HID_ + n] = __float2bfloat16((acc[i][j][e] + bv) * oscale);
      }
    }
  } else if (bn_all < 20) {
#pragma unroll
    for (int j = 0; j < 4; ++j) {
      const int n = bn * 128 + wc * 64 + j * 16 + (lane & 15);
      const float bv = bias[n];
#pragma unroll
      for (int i = 0; i < 4; ++i) {
        const int mb = bm * 128 + wr * 64 + i * 16 + ((lane >> 4) << 2);
#pragma unroll
        for (int e = 0; e < 4; ++e)
          Ck[(size_t)(mb + e) * KVD_ + n] = __float2bfloat16(acc[i][j][e] + bv);
      }
    }
  } else {
    // V^T: [B,KV,D,S], lane holds 4 consecutive s -> packed 8B stores
#pragma unroll
    for (int j = 0; j < 4; ++j) {
      const int n = bn * 128 + wc * 64 + j * 16 + (lane & 15);
      const int kvh = n >> 6, d = n & 63;
      const float bv = bias[n];
#pragma unroll
      for (int i = 0; i < 4; ++i) {
        const int m0 = bm * 128 + wr * 64 + i * 16 + ((lane >> 4) << 2);
        const int b = m0 >> 11, s0 = m0 & (S_ - 1);
        bf16 t4[4];
#pragma unroll
        for (int e = 0; e < 4; ++e) t4[e] = __float2bfloat16(acc[i][j][e] + bv);
        *reinterpret_cast<uint64_t*>(
            Cv + (((size_t)b * KV_ + kvh) * D_ + d) * S_ + s0) =
            *reinterpret_cast<uint64_t*>(t4);
      }
    }
  }
}

// ---------------- output projection: out = A @ Wo^T + bo (f32 out) -------------
__global__ __launch_bounds__(256, 2) void gemm_out(
    const bf16* __restrict__ A, const bf16* __restrict__ W,
    const float* __restrict__ bias, float* __restrict__ C) {
  const int lid0 = blockIdx.y * gridDim.x + blockIdx.x;
  const int q8 = (int)(gridDim.x * gridDim.y) >> 3;
  const int lid = (lid0 & 7) * q8 + (lid0 >> 3);
  const int bm = lid & 31;   // gridDim.x == 32
  const int bn = lid >> 5;

  __shared__ __align__(16) bf16 As[128 * 64];
  __shared__ __align__(16) bf16 Bs[128 * 64];
  const int tid = threadIdx.x;
  const int lane = tid & 63, wid = tid >> 6;
  const int wr = wid >> 1, wc = wid & 1;
  const int K = HID_, N = HID_;

  f32x4 acc[4][4] = {};

  for (int k0 = 0; k0 < K; k0 += 64) {
    __syncthreads();
#pragma unroll
    for (int c = 0; c < 4; ++c) {
      const int r = c * 32 + wid * 8 + (lane >> 3);
      const int gcolb = ((lane & 7) * 16) ^ ((r & 7) << 4);
      gload_lds16(A + (size_t)(bm * 128 + r) * K + k0 + (gcolb >> 1),
                  &As[(c * 32 + wid * 8) * 64]);
      gload_lds16(W + (size_t)(bn * 128 + r) * K + k0 + (gcolb >> 1),
                  &Bs[(c * 32 + wid * 8) * 64]);
    }
    __syncthreads();
#pragma unroll
    for (int ks = 0; ks < 2; ++ks) {
      bf16x8 af[4], bfr[4];
#pragma unroll
      for (int i = 0; i < 4; ++i) {
        const int ra = wr * 64 + i * 16 + (lane & 15);
        const int ka = (ks * 64 + ((lane >> 4) << 4)) ^ ((ra & 7) << 4);
        af[i] = *(const bf16x8*)((const char*)As + ra * 128 + ka);
        const int rb = wc * 64 + i * 16 + (lane & 15);
        const int kb = (ks * 64 + ((lane >> 4) << 4)) ^ ((rb & 7) << 4);
        bfr[i] = *(const bf16x8*)((const char*)Bs + rb * 128 + kb);
      }
      __builtin_amdgcn_s_setprio(1);
#pragma unroll
      for (int i = 0; i < 4; ++i)
#pragma unroll
        for (int j = 0; j < 4; ++j)
          acc[i][j] = __builtin_amdgcn_mfma_f32_16x16x32_bf16(af[i], bfr[j], acc[i][j], 0, 0, 0);
      __builtin_amdgcn_s_setprio(0);
    }
  }

#pragma unroll
  for (int j = 0; j < 4; ++j) {
    const int n = bn * 128 + wc * 64 + j * 16 + (lane & 15);
    const float bv = bias[n];
#pragma unroll
    for (int i = 0; i < 4; ++i) {
      const int mb = bm * 128 + wr * 64 + i * 16 + ((lane >> 4) << 2);
#pragma unroll
      for (int e = 0; e < 4; ++e) {
        C[(size_t)(mb + e) * N + n] = acc[i][j][e] + bv;
      }
    }
  }
}

// ---------------- flash attention (round-10 structure + early V-frag loads) ----
// 4 warps x 64 q-rows (2 chains), swapped QK^T, 32x32 MFMA, KVBLK=64,
// LDS-staged K/V^T (global_load_lds, pre-swizzled source), 1 barrier/tile,
// pipe-overlapped emission. Mask*log2e folded at C-init. l via MFMA (P @ ones).
__global__ __launch_bounds__(256, 2) void attn_fwd(
    const bf16* __restrict__ qb, const bf16* __restrict__ kb,
    const bf16* __restrict__ vtb, const float* __restrict__ mask,
    bf16* __restrict__ ob) {
  // bijective XCD swizzle (512 blocks)
  const int lid0 = blockIdx.y * gridDim.x + blockIdx.x;
  const int q8 = (int)(gridDim.x * gridDim.y) >> 3;
  const int lid = (lid0 & 7) * q8 + (lid0 >> 3);
  const int qtile = lid & 7;      // gridDim.x == 8
  const int headid = lid >> 3;
  const int b = headid >> 5, h = headid & (H_ - 1);
  const int kv = h >> 2;
  const int tid = threadIdx.x, lane = tid & 63, wid = tid >> 6;
  const int l31 = lane & 31, hi = lane >> 5;

  __shared__ __align__(16) bf16 Ks[2][64 * 64];
  __shared__ __align__(16) bf16 VTs[2][64 * 64];  // VT[d][key], source-swizzled

  const bf16* qh = qb + (size_t)b * S_ * HID_ + h * 64;     // row-major [B*S, HID]
  const bf16* kh = kb + (size_t)b * S_ * KVD_ + kv * 64;    // row-major [B*S, KVD]
  const bf16* vth = vtb + (size_t)(b * KV_ + kv) * D_ * S_;
  const float* mrow = mask + (size_t)b * S_;

  // Q B-frags for 2 chains: lane holds q = qs*32 + l31, d = ks*16 + hi*8 + j
  const int qrowbase = qtile * 256 + wid * 64;
  bf16x8 qf[2][4];
#pragma unroll
  for (int qs = 0; qs < 2; ++qs)
#pragma unroll
    for (int ks = 0; ks < 4; ++ks)
      qf[qs][ks] = *(const bf16x8*)(qh + (size_t)(qrowbase + qs * 32 + l31) * HID_ + ks * 16 + hi * 8);

  bf16x8 ones;
#pragma unroll
  for (int i = 0; i < 8; ++i) ones[i] = (short)0x3F80;

  f32x16 o0[2] = {}, o1[2] = {};
  f32x16 lacc0 = {}, lacc1 = {};

  // ---- stage tile 0
#pragma unroll
  for (int c = 0; c < 2; ++c) {
    const int r = c * 32 + wid * 8 + (lane >> 3);
    const int gcolb = ((lane & 7) * 16) ^ ((r & 7) << 4);
    gload_lds16(kh + (size_t)r * KVD_ + (gcolb >> 1), &Ks[0][(c * 32 + wid * 8) * 64]);
    gload_lds16(vth + (size_t)r * S_ + (gcolb >> 1), &VTs[0][(c * 32 + wid * 8) * 64]);
  }
  __syncthreads();

  for (int t = 0; t < NT_; ++t) {
    const int cur = t & 1, nxt = cur ^ 1;

    // ---- prefetch tile t+1 into [nxt]
    if (t < NT_ - 1) {
#pragma unroll
      for (int c = 0; c < 2; ++c) {
        const int r = c * 32 + wid * 8 + (lane >> 3);
        const int gcolb = ((lane & 7) * 16) ^ ((r & 7) << 4);
        gload_lds16(kh + (size_t)((t + 1) * 64 + r) * KVD_ + (gcolb >> 1),
                    &Ks[nxt][(c * 32 + wid * 8) * 64]);
        gload_lds16(vth + (size_t)r * S_ + (t + 1) * 64 + (gcolb >> 1),
                    &VTs[nxt][(c * 32 + wid * 8) * 64]);
      }
    }

    // ---- mask*log2e C-init (key = (r&3) + 8*(r>>2) + 4*hi in C/D layout)
    f32x16 s0[2], s1[2];
#pragma unroll
    for (int kbv = 0; kbv < 2; ++kbv) {
#pragma unroll
      for (int rq = 0; rq < 4; ++rq) {
        const f32x4 m4 = *(const f32x4*)(mrow + t * 64 + kbv * 32 + rq * 8 + 4 * hi);
#pragma unroll
        for (int e = 0; e < 4; ++e) {
          const float mv = m4[e] * LOG2E;
          s0[kbv][rq * 4 + e] = mv;
          s1[kbv][rq * 4 + e] = mv;
        }
      }
    }

    // ---- K frag loads + QK chain0 kbv0 + chain1 kbv0 (K frag reads shared)
    bf16x8 kf0[4], kf1[4];
#pragma unroll
    for (int ks = 0; ks < 4; ++ks) {
      const int rk = l31;
      const int kbyte = (ks * 32 + hi * 16) ^ ((rk & 7) << 4);
      kf0[ks] = *(const bf16x8*)((const char*)&Ks[cur][0] + rk * 128 + kbyte);
    }
    __builtin_amdgcn_s_setprio(1);
#pragma unroll
    for (int ks = 0; ks < 4; ++ks)
      s0[0] = __builtin_amdgcn_mfma_f32_32x32x16_bf16(kf0[ks], qf[0][ks], s0[0], 0, 0, 0);
#pragma unroll
    for (int ks = 0; ks < 4; ++ks)
      s1[0] = __builtin_amdgcn_mfma_f32_32x32x16_bf16(kf0[ks], qf[1][ks], s1[0], 0, 0, 0);
    __builtin_amdgcn_s_setprio(0);
#pragma unroll
    for (int ks = 0; ks < 4; ++ks) {
      const int rk = 32 + l31;
      const int kbyte = (ks * 32 + hi * 16) ^ ((rk & 7) << 4);
      kf1[ks] = *(const bf16x8*)((const char*)&Ks[cur][0] + rk * 128 + kbyte);
    }
    // V frags issued EARLY: their LDS latency hides under softmax(c0) below
    bf16x8 vf[2][4];
#pragma unroll
    for (int db = 0; db < 2; ++db)
#pragma unroll
      for (int kk = 0; kk < 4; ++kk) {
        const int kbv = kk >> 1, ks2 = kk & 1;
        const int rd = db * 32 + l31;
        const int vbyte = (kbv * 64 + ks2 * 32 + hi * 16) ^ ((rd & 7) << 4);
        vf[db][kk] = *(const bf16x8*)((const char*)&VTs[cur][0] + rd * 128 + vbyte);
      }
    __builtin_amdgcn_s_setprio(1);
#pragma unroll
    for (int ks = 0; ks < 4; ++ks)
      s0[1] = __builtin_amdgcn_mfma_f32_32x32x16_bf16(kf1[ks], qf[0][ks], s0[1], 0, 0, 0);
    __builtin_amdgcn_s_setprio(0);

    // ---- softmax chain0 kbv0 (overlaps s0[1] MFMAs in the pipe)
    bf16x8 pa0[2][2], pa1[2][2];
#pragma unroll
    for (int r = 0; r < 16; ++r) s0[0][r] = fexp2(s0[0][r]);
    {
      uint32_t a0 = cvtpk_bf16(s0[0][0], s0[0][1]);
      uint32_t b0 = cvtpk_bf16(s0[0][4], s0[0][5]);
      plane32_swap(a0, b0);
      uint32_t a1 = cvtpk_bf16(s0[0][2], s0[0][3]);
      uint32_t b1 = cvtpk_bf16(s0[0][6], s0[0][7]);
      plane32_swap(a1, b1);
      i32x4 t0; t0[0] = (int)a0; t0[1] = (int)a1; t0[2] = (int)b0; t0[3] = (int)b1;
      pa0[0][0] = __builtin_bit_cast(bf16x8, t0);
      uint32_t a2 = cvtpk_bf16(s0[0][8], s0[0][9]);
      uint32_t b2 = cvtpk_bf16(s0[0][12], s0[0][13]);
      plane32_swap(a2, b2);
      uint32_t a3 = cvtpk_bf16(s0[0][10], s0[0][11]);
      uint32_t b3 = cvtpk_bf16(s0[0][14], s0[0][15]);
      plane32_swap(a3, b3);
      i32x4 t1; t1[0] = (int)a2; t1[1] = (int)a3; t1[2] = (int)b2; t1[3] = (int)b3;
      pa0[0][1] = __builtin_bit_cast(bf16x8, t1);
    }

    // ---- QK chain1 kbv1
    __builtin_amdgcn_s_setprio(1);
#pragma unroll
    for (int ks = 0; ks < 4; ++ks)
      s1[1] = __builtin_amdgcn_mfma_f32_32x32x16_bf16(kf1[ks], qf[1][ks], s1[1], 0, 0, 0);
    __builtin_amdgcn_s_setprio(0);

    // ---- softmax chain0 kbv1 (overlaps s1[1] MFMAs)
#pragma unroll
    for (int r = 0; r < 16; ++r) s0[1][r] = fexp2(s0[1][r]);
    {
      uint32_t a0 = cvtpk_bf16(s0[1][0], s0[1][1]);
      uint32_t b0 = cvtpk_bf16(s0[1][4], s0[1][5]);
      plane32_swap(a0, b0);
      uint32_t a1 = cvtpk_bf16(s0[1][2], s0[1][3]);
      uint32_t b1 = cvtpk_bf16(s0[1][6], s0[1][7]);
      plane32_swap(a1, b1);
      i32x4 t0; t0[0] = (int)a0; t0[1] = (int)a1; t0[2] = (int)b0; t0[3] = (int)b1;
      pa0[1][0] = __builtin_bit_cast(bf16x8, t0);
      uint32_t a2 = cvtpk_bf16(s0[1][8], s0[1][9]);
      uint32_t b2 = cvtpk_bf16(s0[1][12], s0[1][13]);
      plane32_swap(a2, b2);
      uint32_t a3 = cvtpk_bf16(s0[1][10], s0[1][11]);
      uint32_t b3 = cvtpk_bf16(s0[1][14], s0[1][15]);
      plane32_swap(a3, b3);
      i32x4 t1; t1[0] = (int)a2; t1[1] = (int)a3; t1[2] = (int)b2; t1[3] = (int)b3;
      pa0[1][1] = __builtin_bit_cast(bf16x8, t1);
    }

    // ---- l(c0) + PV(c0)  (softmax(c1) below overlaps these MFMAs)
    __builtin_amdgcn_s_setprio(1);
#pragma unroll
    for (int kk = 0; kk < 4; ++kk)
      lacc0 = __builtin_amdgcn_mfma_f32_32x32x16_bf16(pa0[kk >> 1][kk & 1], ones, lacc0, 0, 0, 0);
#pragma unroll
    for (int db = 0; db < 2; ++db)
#pragma unroll
      for (int kk = 0; kk < 4; ++kk)
        o0[db] = __builtin_amdgcn_mfma_f32_32x32x16_bf16(pa0[kk >> 1][kk & 1], vf[db][kk], o0[db], 0, 0, 0);
    __builtin_amdgcn_s_setprio(0);

    // ---- softmax chain1 (both kbv)
#pragma unroll
    for (int kbv = 0; kbv < 2; ++kbv) {
#pragma unroll
      for (int r = 0; r < 16; ++r) s1[kbv][r] = fexp2(s1[kbv][r]);
      uint32_t a0 = cvtpk_bf16(s1[kbv][0], s1[kbv][1]);
      uint32_t b0 = cvtpk_bf16(s1[kbv][4], s1[kbv][5]);
      plane32_swap(a0, b0);
      uint32_t a1 = cvtpk_bf16(s1[kbv][2], s1[kbv][3]);
      uint32_t b1 = cvtpk_bf16(s1[kbv][6], s1[kbv][7]);
      plane32_swap(a1, b1);
      i32x4 t0; t0[0] = (int)a0; t0[1] = (int)a1; t0[2] = (int)b0; t0[3] = (int)b1;
      pa1[kbv][0] = __builtin_bit_cast(bf16x8, t0);
      uint32_t a2 = cvtpk_bf16(s1[kbv][8], s1[kbv][9]);
      uint32_t b2 = cvtpk_bf16(s1[kbv][12], s1[kbv][13]);
      plane32_swap(a2, b2);
      uint32_t a3 = cvtpk_bf16(s1[kbv][10], s1[kbv][11]);
      uint32_t b3 = cvtpk_bf16(s1[kbv][14], s1[kbv][15]);
      plane32_swap(a3, b3);
      i32x4 t1; t1[0] = (int)a2; t1[1] = (int)a3; t1[2] = (int)b2; t1[3] = (int)b3;
      pa1[kbv][1] = __builtin_bit_cast(bf16x8, t1);
    }

    // ---- l(c1) + PV(c1)
    __builtin_amdgcn_s_setprio(1);
#pragma unroll
    for (int kk = 0; kk < 4; ++kk)
      lacc1 = __builtin_amdgcn_mfma_f32_32x32x16_bf16(pa1[kk >> 1][kk & 1], ones, lacc1, 0, 0, 0);
#pragma unroll
    for (int db = 0; db < 2; ++db)
#pragma unroll
      for (int kk = 0; kk < 4; ++kk)
        o1[db] = __builtin_amdgcn_mfma_f32_32x32x16_bf16(pa1[kk >> 1][kk & 1], vf[db][kk], o1[db], 0, 0, 0);
    __builtin_amdgcn_s_setprio(0);

    __syncthreads();  // drains prefetch + guards [cur] reuse
  }

  // ---- epilogue: lacc is in the SAME C/D layout as o -> direct divide
#pragma unroll
  for (int r = 0; r < 16; ++r) {
    const int q_out = (r & 3) + 8 * (r >> 2) + 4 * hi;
    {
      const float inv = 1.0f / lacc0[r];
      const int srow = qrowbase + q_out;
      ob[((size_t)b * S_ + srow) * HID_ + h * 64 + l31] = __float2bfloat16(o0[0][r] * inv);
      ob[((size_t)b * S_ + srow) * HID_ + h * 64 + 32 + l31] = __float2bfloat16(o0[1][r] * inv);
    }
    {
      const float inv = 1.0f / lacc1[r];
      const int srow = qrowbase + 32 + q_out;
      ob[((size_t)b * S_ + srow) * HID_ + h * 64 + l31] = __float2bfloat16(o1[0][r] * inv);
      ob[((size_t)b * S_ + srow) * HID_ + h * 64 + 32 + l31] = __float2bfloat16(o1[1][r] * inv);
    }
  }
}

extern "C" void kernel_launch(void* const* d_in, const int* in_sizes, int n_in,
                              void* d_out, int out_size, void* d_ws, size_t ws_size,
                              hipStream_t stream) {
  (void)in_sizes; (void)n_in; (void)out_size; (void)ws_size;
  const float* x  = (const float*)d_in[0];
  const float* am = (const float*)d_in[1];
  const float* Wq = (const float*)d_in[2];
  const float* bq = (const float*)d_in[3];
  const float* Wk = (const float*)d_in[4];
  const float* bk = (const float*)d_in[5];
  const float* Wv = (const float*)d_in[6];
  const float* bv = (const float*)d_in[7];
  const float* Wo = (const float*)d_in[8];
  const float* bo = (const float*)d_in[9];
  float* out = (float*)d_out;

  const size_t XE  = (size_t)B_ * S_ * HID_;
  const size_t WQE = (size_t)HID_ * HID_;
  const size_t WKE = (size_t)KVD_ * HID_;
  const size_t QE  = (size_t)B_ * S_ * HID_;
  const size_t KE  = (size_t)B_ * S_ * KVD_;

  bf16* xb  = (bf16*)d_ws;
  bf16* wqb = xb + XE;
  bf16* wkb = wqb + WQE;
  bf16* wvb = wkb + WKE;
  bf16* wob = wvb + WKE;
  bf16* qbuf = wob + WQE;     // Q row-major [B*S, HID]
  bf16* kbuf = qbuf + QE;     // K row-major [B*S, KVD]
  bf16* vtbuf = kbuf + KE;    // V^T [B,KV,D,S]
  bf16* abuf = vtbuf + KE;    // attn out [B,S,HID]

  dim3 blk(256);
  CvtJob jx  = { x,  xb,  (int)(XE / 4) };
  CvtJob jwq = { Wq, wqb, (int)(WQE / 4) };
  CvtJob jwk = { Wk, wkb, (int)(WKE / 4) };
  CvtJob jwv = { Wv, wvb, (int)(WKE / 4) };
  CvtJob jwo = { Wo, wob, (int)(WQE / 4) };
  cvt_multi<<<dim3(512, 5), blk, 0, stream>>>(jx, jwq, jwk, jwv, jwo);

  const int M = B_ * S_;
  gemm_qkv<<<dim3(M / 128, 24), blk, 0, stream>>>(xb, wqb, wkb, wvb, bq, bk, bv,
                                                  qbuf, kbuf, vtbuf);
  attn_fwd<<<dim3(S_ / 256, B_ * H_), blk, 0, stream>>>(qbuf, kbuf, vtbuf, am, abuf);
  gemm_out<<<dim3(M / 128, HID_ / 128), blk, 0, stream>>>(abuf, wob, bo, out);
}

// Round 13
// 189.438 us; speedup vs baseline: 1.1012x; 1.1012x over previous
//
#include <hip/hip_runtime.h>
#include <hip/hip_bf16.h>
#include <stdint.h>

typedef __hip_bfloat16 bf16;
typedef __attribute__((ext_vector_type(8))) short bf16x8;
typedef __attribute__((ext_vector_type(4))) float f32x4;
typedef __attribute__((ext_vector_type(16))) float f32x16;
typedef __attribute__((ext_vector_type(4))) int i32x4;
typedef __attribute__((ext_vector_type(2))) int i32x2;

#define B_   2
#define S_   2048
#define HID_ 2048
#define H_   32
#define KV_  8
#define D_   64
#define KVD_ (KV_ * D_)
#define NT_  (S_ / 64)
#define LOG2E 1.4426950408889634f

__device__ __forceinline__ void gload_lds16(const void* g, void* l) {
  __builtin_amdgcn_global_load_lds(
      (const __attribute__((address_space(1))) uint32_t*)g,
      (__attribute__((address_space(3))) uint32_t*)l, 16, 0, 0);
}
__device__ __forceinline__ float fexp2(float x) { return __builtin_amdgcn_exp2f(x); }

__device__ __forceinline__ uint32_t cvtpk_bf16(float lo, float hi) {
  uint32_t r;
  asm("v_cvt_pk_bf16_f32 %0, %1, %2" : "=v"(r) : "v"(lo), "v"(hi));
  return r;
}
__device__ __forceinline__ void plane32_swap(uint32_t& a, uint32_t& b) {
  i32x2 r = __builtin_amdgcn_permlane32_swap((int)a, (int)b, false, false);
  a = (uint32_t)r[0]; b = (uint32_t)r[1];
}

// ---- fused f32 -> bf16 conversion over 5 buffers (one launch) ----
struct CvtJob { const float* s; bf16* d; int n4; };
__global__ __launch_bounds__(256) void cvt_multi(
    CvtJob j0, CvtJob j1, CvtJob j2, CvtJob j3, CvtJob j4) {
  CvtJob j;
  switch (blockIdx.y) {
    case 0: j = j0; break;
    case 1: j = j1; break;
    case 2: j = j2; break;
    case 3: j = j3; break;
    default: j = j4; break;
  }
  int i = blockIdx.x * blockDim.x + threadIdx.x;
  const int stride = gridDim.x * blockDim.x;
  for (; i < j.n4; i += stride) {
    float4 v = ((const float4*)j.s)[i];
    bf16 t[4];
    t[0] = __float2bfloat16(v.x);
    t[1] = __float2bfloat16(v.y);
    t[2] = __float2bfloat16(v.z);
    t[3] = __float2bfloat16(v.w);
    *reinterpret_cast<uint64_t*>(j.d + 4 * (size_t)i) = *reinterpret_cast<uint64_t*>(t);
  }
}

// ---------------- fused QKV projection ----------------
// Q (scaled by 0.125*log2e) -> row-major [B*S, HID].
// K -> row-major [B*S, KVD]. V -> transposed [B,KV,D,S].
__global__ __launch_bounds__(256, 3) void gemm_qkv(
    const bf16* __restrict__ A,
    const bf16* __restrict__ Wqp, const bf16* __restrict__ Wkp, const bf16* __restrict__ Wvp,
    const float* __restrict__ bqp, const float* __restrict__ bkp, const float* __restrict__ bvp,
    bf16* __restrict__ Cq, bf16* __restrict__ Ck, bf16* __restrict__ Cv) {
  const int lid0 = blockIdx.y * gridDim.x + blockIdx.x;
  const int q8 = (int)(gridDim.x * gridDim.y) >> 3;
  const int lid = (lid0 & 7) * q8 + (lid0 >> 3);
  const int bm = lid & 31;        // gridDim.x == 32
  const int bn_all = lid >> 5;

  const bf16* W; const float* bias; int bn;
  if (bn_all < 16)      { W = Wqp; bias = bqp; bn = bn_all; }
  else if (bn_all < 20) { W = Wkp; bias = bkp; bn = bn_all - 16; }
  else                  { W = Wvp; bias = bvp; bn = bn_all - 20; }
  const float oscale = (bn_all < 16) ? (0.125f * LOG2E) : 1.0f;

  __shared__ __align__(16) bf16 As[128 * 64];
  __shared__ __align__(16) bf16 Bs[128 * 64];
  const int tid = threadIdx.x;
  const int lane = tid & 63, wid = tid >> 6;
  const int wr = wid >> 1, wc = wid & 1;
  const int K = HID_;

  f32x4 acc[4][4] = {};

  for (int k0 = 0; k0 < K; k0 += 64) {
    __syncthreads();
#pragma unroll
    for (int c = 0; c < 4; ++c) {
      const int r = c * 32 + wid * 8 + (lane >> 3);
      const int gcolb = ((lane & 7) * 16) ^ ((r & 7) << 4);
      gload_lds16(A + (size_t)(bm * 128 + r) * K + k0 + (gcolb >> 1),
                  &As[(c * 32 + wid * 8) * 64]);
      gload_lds16(W + (size_t)(bn * 128 + r) * K + k0 + (gcolb >> 1),
                  &Bs[(c * 32 + wid * 8) * 64]);
    }
    __syncthreads();
#pragma unroll
    for (int ks = 0; ks < 2; ++ks) {
      bf16x8 af[4], bfr[4];
#pragma unroll
      for (int i = 0; i < 4; ++i) {
        const int ra = wr * 64 + i * 16 + (lane & 15);
        const int ka = (ks * 64 + ((lane >> 4) << 4)) ^ ((ra & 7) << 4);
        af[i] = *(const bf16x8*)((const char*)As + ra * 128 + ka);
        const int rb = wc * 64 + i * 16 + (lane & 15);
        const int kb = (ks * 64 + ((lane >> 4) << 4)) ^ ((rb & 7) << 4);
        bfr[i] = *(const bf16x8*)((const char*)Bs + rb * 128 + kb);
      }
      __builtin_amdgcn_s_setprio(1);
#pragma unroll
      for (int i = 0; i < 4; ++i)
#pragma unroll
        for (int j = 0; j < 4; ++j)
          acc[i][j] = __builtin_amdgcn_mfma_f32_16x16x32_bf16(af[i], bfr[j], acc[i][j], 0, 0, 0);
      __builtin_amdgcn_s_setprio(0);
    }
  }

  if (bn_all < 16) {
#pragma unroll
    for (int j = 0; j < 4; ++j) {
      const int n = bn * 128 + wc * 64 + j * 16 + (lane & 15);
      const float bv = bias[n];
#pragma unroll
      for (int i = 0; i < 4; ++i) {
        const int mb = bm * 128 + wr * 64 + i * 16 + ((lane >> 4) << 2);
#pragma unroll
        for (int e = 0; e < 4; ++e)
          Cq[(size_t)(mb + e) * HID_ + n] = __float2bfloat16((acc[i][j][e] + bv) * oscale);
      }
    }
  } else if (bn_all < 20) {
#pragma unroll
    for (int j = 0; j < 4; ++j) {
      const int n = bn * 128 + wc * 64 + j * 16 + (lane & 15);
      const float bv = bias[n];
#pragma unroll
      for (int i = 0; i < 4; ++i) {
        const int mb = bm * 128 + wr * 64 + i * 16 + ((lane >> 4) << 2);
#pragma unroll
        for (int e = 0; e < 4; ++e)
          Ck[(size_t)(mb + e) * KVD_ + n] = __float2bfloat16(acc[i][j][e] + bv);
      }
    }
  } else {
    // V^T: [B,KV,D,S], lane holds 4 consecutive s -> packed 8B stores
#pragma unroll
    for (int j = 0; j < 4; ++j) {
      const int n = bn * 128 + wc * 64 + j * 16 + (lane & 15);
      const int kvh = n >> 6, d = n & 63;
      const float bv = bias[n];
#pragma unroll
      for (int i = 0; i < 4; ++i) {
        const int m0 = bm * 128 + wr * 64 + i * 16 + ((lane >> 4) << 2);
        const int b = m0 >> 11, s0 = m0 & (S_ - 1);
        bf16 t4[4];
#pragma unroll
        for (int e = 0; e < 4; ++e) t4[e] = __float2bfloat16(acc[i][j][e] + bv);
        *reinterpret_cast<uint64_t*>(
            Cv + (((size_t)b * KV_ + kvh) * D_ + d) * S_ + s0) =
            *reinterpret_cast<uint64_t*>(t4);
      }
    }
  }
}

// ---------------- output projection: out = A @ Wo^T + bo (f32 out) -------------
__global__ __launch_bounds__(256, 2) void gemm_out(
    const bf16* __restrict__ A, const bf16* __restrict__ W,
    const float* __restrict__ bias, float* __restrict__ C) {
  const int lid0 = blockIdx.y * gridDim.x + blockIdx.x;
  const int q8 = (int)(gridDim.x * gridDim.y) >> 3;
  const int lid = (lid0 & 7) * q8 + (lid0 >> 3);
  const int bm = lid & 31;   // gridDim.x == 32
  const int bn = lid >> 5;

  __shared__ __align__(16) bf16 As[128 * 64];
  __shared__ __align__(16) bf16 Bs[128 * 64];
  const int tid = threadIdx.x;
  const int lane = tid & 63, wid = tid >> 6;
  const int wr = wid >> 1, wc = wid & 1;
  const int K = HID_, N = HID_;

  f32x4 acc[4][4] = {};

  for (int k0 = 0; k0 < K; k0 += 64) {
    __syncthreads();
#pragma unroll
    for (int c = 0; c < 4; ++c) {
      const int r = c * 32 + wid * 8 + (lane >> 3);
      const int gcolb = ((lane & 7) * 16) ^ ((r & 7) << 4);
      gload_lds16(A + (size_t)(bm * 128 + r) * K + k0 + (gcolb >> 1),
                  &As[(c * 32 + wid * 8) * 64]);
      gload_lds16(W + (size_t)(bn * 128 + r) * K + k0 + (gcolb >> 1),
                  &Bs[(c * 32 + wid * 8) * 64]);
    }
    __syncthreads();
#pragma unroll
    for (int ks = 0; ks < 2; ++ks) {
      bf16x8 af[4], bfr[4];
#pragma unroll
      for (int i = 0; i < 4; ++i) {
        const int ra = wr * 64 + i * 16 + (lane & 15);
        const int ka = (ks * 64 + ((lane >> 4) << 4)) ^ ((ra & 7) << 4);
        af[i] = *(const bf16x8*)((const char*)As + ra * 128 + ka);
        const int rb = wc * 64 + i * 16 + (lane & 15);
        const int kb = (ks * 64 + ((lane >> 4) << 4)) ^ ((rb & 7) << 4);
        bfr[i] = *(const bf16x8*)((const char*)Bs + rb * 128 + kb);
      }
      __builtin_amdgcn_s_setprio(1);
#pragma unroll
      for (int i = 0; i < 4; ++i)
#pragma unroll
        for (int j = 0; j < 4; ++j)
          acc[i][j] = __builtin_amdgcn_mfma_f32_16x16x32_bf16(af[i], bfr[j], acc[i][j], 0, 0, 0);
      __builtin_amdgcn_s_setprio(0);
    }
  }

#pragma unroll
  for (int j = 0; j < 4; ++j) {
    const int n = bn * 128 + wc * 64 + j * 16 + (lane & 15);
    const float bv = bias[n];
#pragma unroll
    for (int i = 0; i < 4; ++i) {
      const int mb = bm * 128 + wr * 64 + i * 16 + ((lane >> 4) << 2);
#pragma unroll
      for (int e = 0; e < 4; ++e) {
        C[(size_t)(mb + e) * N + n] = acc[i][j][e] + bv;
      }
    }
  }
}

// ---------------- flash attention (round-10 structure, inline mask*log2e) ----
// 4 warps x 64 q-rows (2 chains), swapped QK^T, 32x32 MFMA, KVBLK=64,
// LDS-staged K/V^T (global_load_lds, pre-swizzled source), 1 barrier/tile,
// pipe-overlapped emission. V frags loaded LATE (minimal live range — the
// round-12 hoist caused scratch spills). l via MFMA (P @ ones).
__global__ __launch_bounds__(256, 2) void attn_fwd(
    const bf16* __restrict__ qb, const bf16* __restrict__ kb,
    const bf16* __restrict__ vtb, const float* __restrict__ mask,
    bf16* __restrict__ ob) {
  // bijective XCD swizzle (512 blocks)
  const int lid0 = blockIdx.y * gridDim.x + blockIdx.x;
  const int q8 = (int)(gridDim.x * gridDim.y) >> 3;
  const int lid = (lid0 & 7) * q8 + (lid0 >> 3);
  const int qtile = lid & 7;      // gridDim.x == 8
  const int headid = lid >> 3;
  const int b = headid >> 5, h = headid & (H_ - 1);
  const int kv = h >> 2;
  const int tid = threadIdx.x, lane = tid & 63, wid = tid >> 6;
  const int l31 = lane & 31, hi = lane >> 5;

  __shared__ __align__(16) bf16 Ks[2][64 * 64];
  __shared__ __align__(16) bf16 VTs[2][64 * 64];  // VT[d][key], source-swizzled

  const bf16* qh = qb + (size_t)b * S_ * HID_ + h * 64;     // row-major [B*S, HID]
  const bf16* kh = kb + (size_t)b * S_ * KVD_ + kv * 64;    // row-major [B*S, KVD]
  const bf16* vth = vtb + (size_t)(b * KV_ + kv) * D_ * S_;
  const float* mrow = mask + (size_t)b * S_;

  // Q B-frags for 2 chains: lane holds q = qs*32 + l31, d = ks*16 + hi*8 + j
  const int qrowbase = qtile * 256 + wid * 64;
  bf16x8 qf[2][4];
#pragma unroll
  for (int qs = 0; qs < 2; ++qs)
#pragma unroll
    for (int ks = 0; ks < 4; ++ks)
      qf[qs][ks] = *(const bf16x8*)(qh + (size_t)(qrowbase + qs * 32 + l31) * HID_ + ks * 16 + hi * 8);

  bf16x8 ones;
#pragma unroll
  for (int i = 0; i < 8; ++i) ones[i] = (short)0x3F80;

  f32x16 o0[2] = {}, o1[2] = {};
  f32x16 lacc0 = {}, lacc1 = {};

  // ---- stage tile 0
#pragma unroll
  for (int c = 0; c < 2; ++c) {
    const int r = c * 32 + wid * 8 + (lane >> 3);
    const int gcolb = ((lane & 7) * 16) ^ ((r & 7) << 4);
    gload_lds16(kh + (size_t)r * KVD_ + (gcolb >> 1), &Ks[0][(c * 32 + wid * 8) * 64]);
    gload_lds16(vth + (size_t)r * S_ + (gcolb >> 1), &VTs[0][(c * 32 + wid * 8) * 64]);
  }
  __syncthreads();

  for (int t = 0; t < NT_; ++t) {
    const int cur = t & 1, nxt = cur ^ 1;

    // ---- prefetch tile t+1 into [nxt]
    if (t < NT_ - 1) {
#pragma unroll
      for (int c = 0; c < 2; ++c) {
        const int r = c * 32 + wid * 8 + (lane >> 3);
        const int gcolb = ((lane & 7) * 16) ^ ((r & 7) << 4);
        gload_lds16(kh + (size_t)((t + 1) * 64 + r) * KVD_ + (gcolb >> 1),
                    &Ks[nxt][(c * 32 + wid * 8) * 64]);
        gload_lds16(vth + (size_t)r * S_ + (t + 1) * 64 + (gcolb >> 1),
                    &VTs[nxt][(c * 32 + wid * 8) * 64]);
      }
    }

    // ---- mask*log2e C-init (key = (r&3) + 8*(r>>2) + 4*hi in C/D layout)
    f32x16 s0[2], s1[2];
#pragma unroll
    for (int kbv = 0; kbv < 2; ++kbv) {
#pragma unroll
      for (int rq = 0; rq < 4; ++rq) {
        const f32x4 m4 = *(const f32x4*)(mrow + t * 64 + kbv * 32 + rq * 8 + 4 * hi);
#pragma unroll
        for (int e = 0; e < 4; ++e) {
          const float mv = m4[e] * LOG2E;
          s0[kbv][rq * 4 + e] = mv;
          s1[kbv][rq * 4 + e] = mv;
        }
      }
    }

    // ---- QK chain0 kbv0 + chain1 kbv0 (K frag reads shared)
    bf16x8 kf0[4], kf1[4];
#pragma unroll
    for (int ks = 0; ks < 4; ++ks) {
      const int rk = l31;
      const int kbyte = (ks * 32 + hi * 16) ^ ((rk & 7) << 4);
      kf0[ks] = *(const bf16x8*)((const char*)&Ks[cur][0] + rk * 128 + kbyte);
    }
    __builtin_amdgcn_s_setprio(1);
#pragma unroll
    for (int ks = 0; ks < 4; ++ks)
      s0[0] = __builtin_amdgcn_mfma_f32_32x32x16_bf16(kf0[ks], qf[0][ks], s0[0], 0, 0, 0);
#pragma unroll
    for (int ks = 0; ks < 4; ++ks)
      s1[0] = __builtin_amdgcn_mfma_f32_32x32x16_bf16(kf0[ks], qf[1][ks], s1[0], 0, 0, 0);
    __builtin_amdgcn_s_setprio(0);
#pragma unroll
    for (int ks = 0; ks < 4; ++ks) {
      const int rk = 32 + l31;
      const int kbyte = (ks * 32 + hi * 16) ^ ((rk & 7) << 4);
      kf1[ks] = *(const bf16x8*)((const char*)&Ks[cur][0] + rk * 128 + kbyte);
    }
    __builtin_amdgcn_s_setprio(1);
#pragma unroll
    for (int ks = 0; ks < 4; ++ks)
      s0[1] = __builtin_amdgcn_mfma_f32_32x32x16_bf16(kf1[ks], qf[0][ks], s0[1], 0, 0, 0);
    __builtin_amdgcn_s_setprio(0);

    // ---- softmax chain0 kbv0 (overlaps s0[1] MFMAs in the pipe)
    bf16x8 pa0[2][2], pa1[2][2];
#pragma unroll
    for (int r = 0; r < 16; ++r) s0[0][r] = fexp2(s0[0][r]);
    {
      uint32_t a0 = cvtpk_bf16(s0[0][0], s0[0][1]);
      uint32_t b0 = cvtpk_bf16(s0[0][4], s0[0][5]);
      plane32_swap(a0, b0);
      uint32_t a1 = cvtpk_bf16(s0[0][2], s0[0][3]);
      uint32_t b1 = cvtpk_bf16(s0[0][6], s0[0][7]);
      plane32_swap(a1, b1);
      i32x4 t0; t0[0] = (int)a0; t0[1] = (int)a1; t0[2] = (int)b0; t0[3] = (int)b1;
      pa0[0][0] = __builtin_bit_cast(bf16x8, t0);
      uint32_t a2 = cvtpk_bf16(s0[0][8], s0[0][9]);
      uint32_t b2 = cvtpk_bf16(s0[0][12], s0[0][13]);
      plane32_swap(a2, b2);
      uint32_t a3 = cvtpk_bf16(s0[0][10], s0[0][11]);
      uint32_t b3 = cvtpk_bf16(s0[0][14], s0[0][15]);
      plane32_swap(a3, b3);
      i32x4 t1; t1[0] = (int)a2; t1[1] = (int)a3; t1[2] = (int)b2; t1[3] = (int)b3;
      pa0[0][1] = __builtin_bit_cast(bf16x8, t1);
    }

    // ---- QK chain1 kbv1
    __builtin_amdgcn_s_setprio(1);
#pragma unroll
    for (int ks = 0; ks < 4; ++ks)
      s1[1] = __builtin_amdgcn_mfma_f32_32x32x16_bf16(kf1[ks], qf[1][ks], s1[1], 0, 0, 0);
    __builtin_amdgcn_s_setprio(0);

    // ---- softmax chain0 kbv1 (overlaps s1[1] MFMAs)
#pragma unroll
    for (int r = 0; r < 16; ++r) s0[1][r] = fexp2(s0[1][r]);
    {
      uint32_t a0 = cvtpk_bf16(s0[1][0], s0[1][1]);
      uint32_t b0 = cvtpk_bf16(s0[1][4], s0[1][5]);
      plane32_swap(a0, b0);
      uint32_t a1 = cvtpk_bf16(s0[1][2], s0[1][3]);
      uint32_t b1 = cvtpk_bf16(s0[1][6], s0[1][7]);
      plane32_swap(a1, b1);
      i32x4 t0; t0[0] = (int)a0; t0[1] = (int)a1; t0[2] = (int)b0; t0[3] = (int)b1;
      pa0[1][0] = __builtin_bit_cast(bf16x8, t0);
      uint32_t a2 = cvtpk_bf16(s0[1][8], s0[1][9]);
      uint32_t b2 = cvtpk_bf16(s0[1][12], s0[1][13]);
      plane32_swap(a2, b2);
      uint32_t a3 = cvtpk_bf16(s0[1][10], s0[1][11]);
      uint32_t b3 = cvtpk_bf16(s0[1][14], s0[1][15]);
      plane32_swap(a3, b3);
      i32x4 t1; t1[0] = (int)a2; t1[1] = (int)a3; t1[2] = (int)b2; t1[3] = (int)b3;
      pa0[1][1] = __builtin_bit_cast(bf16x8, t1);
    }

    // ---- V frags (late load: minimal live range)
    bf16x8 vf[2][4];
#pragma unroll
    for (int db = 0; db < 2; ++db)
#pragma unroll
      for (int kk = 0; kk < 4; ++kk) {
        const int kbv = kk >> 1, ks2 = kk & 1;
        const int rd = db * 32 + l31;
        const int vbyte = (kbv * 64 + ks2 * 32 + hi * 16) ^ ((rd & 7) << 4);
        vf[db][kk] = *(const bf16x8*)((const char*)&VTs[cur][0] + rd * 128 + vbyte);
      }

    // ---- l(c0) + PV(c0)  (softmax(c1) below overlaps these MFMAs)
    __builtin_amdgcn_s_setprio(1);
#pragma unroll
    for (int kk = 0; kk < 4; ++kk)
      lacc0 = __builtin_amdgcn_mfma_f32_32x32x16_bf16(pa0[kk >> 1][kk & 1], ones, lacc0, 0, 0, 0);
#pragma unroll
    for (int db = 0; db < 2; ++db)
#pragma unroll
      for (int kk = 0; kk < 4; ++kk)
        o0[db] = __builtin_amdgcn_mfma_f32_32x32x16_bf16(pa0[kk >> 1][kk & 1], vf[db][kk], o0[db], 0, 0, 0);
    __builtin_amdgcn_s_setprio(0);

    // ---- softmax chain1 (both kbv)
#pragma unroll
    for (int kbv = 0; kbv < 2; ++kbv) {
#pragma unroll
      for (int r = 0; r < 16; ++r) s1[kbv][r] = fexp2(s1[kbv][r]);
      uint32_t a0 = cvtpk_bf16(s1[kbv][0], s1[kbv][1]);
      uint32_t b0 = cvtpk_bf16(s1[kbv][4], s1[kbv][5]);
      plane32_swap(a0, b0);
      uint32_t a1 = cvtpk_bf16(s1[kbv][2], s1[kbv][3]);
      uint32_t b1 = cvtpk_bf16(s1[kbv][6], s1[kbv][7]);
      plane32_swap(a1, b1);
      i32x4 t0; t0[0] = (int)a0; t0[1] = (int)a1; t0[2] = (int)b0; t0[3] = (int)b1;
      pa1[kbv][0] = __builtin_bit_cast(bf16x8, t0);
      uint32_t a2 = cvtpk_bf16(s1[kbv][8], s1[kbv][9]);
      uint32_t b2 = cvtpk_bf16(s1[kbv][12], s1[kbv][13]);
      plane32_swap(a2, b2);
      uint32_t a3 = cvtpk_bf16(s1[kbv][10], s1[kbv][11]);
      uint32_t b3 = cvtpk_bf16(s1[kbv][14], s1[kbv][15]);
      plane32_swap(a3, b3);
      i32x4 t1; t1[0] = (int)a2; t1[1] = (int)a3; t1[2] = (int)b2; t1[3] = (int)b3;
      pa1[kbv][1] = __builtin_bit_cast(bf16x8, t1);
    }

    // ---- l(c1) + PV(c1)
    __builtin_amdgcn_s_setprio(1);
#pragma unroll
    for (int kk = 0; kk < 4; ++kk)
      lacc1 = __builtin_amdgcn_mfma_f32_32x32x16_bf16(pa1[kk >> 1][kk & 1], ones, lacc1, 0, 0, 0);
#pragma unroll
    for (int db = 0; db < 2; ++db)
#pragma unroll
      for (int kk = 0; kk < 4; ++kk)
        o1[db] = __builtin_amdgcn_mfma_f32_32x32x16_bf16(pa1[kk >> 1][kk & 1], vf[db][kk], o1[db], 0, 0, 0);
    __builtin_amdgcn_s_setprio(0);

    __syncthreads();  // drains prefetch + guards [cur] reuse
  }

  // ---- epilogue: lacc is in the SAME C/D layout as o -> direct divide
#pragma unroll
  for (int r = 0; r < 16; ++r) {
    const int q_out = (r & 3) + 8 * (r >> 2) + 4 * hi;
    {
      const float inv = 1.0f / lacc0[r];
      const int srow = qrowbase + q_out;
      ob[((size_t)b * S_ + srow) * HID_ + h * 64 + l31] = __float2bfloat16(o0[0][r] * inv);
      ob[((size_t)b * S_ + srow) * HID_ + h * 64 + 32 + l31] = __float2bfloat16(o0[1][r] * inv);
    }
    {
      const float inv = 1.0f / lacc1[r];
      const int srow = qrowbase + 32 + q_out;
      ob[((size_t)b * S_ + srow) * HID_ + h * 64 + l31] = __float2bfloat16(o1[0][r] * inv);
      ob[((size_t)b * S_ + srow) * HID_ + h * 64 + 32 + l31] = __float2bfloat16(o1[1][r] * inv);
    }
  }
}

extern "C" void kernel_launch(void* const* d_in, const int* in_sizes, int n_in,
                              void* d_out, int out_size, void* d_ws, size_t ws_size,
                              hipStream_t stream) {
  (void)in_sizes; (void)n_in; (void)out_size; (void)ws_size;
  const float* x  = (const float*)d_in[0];
  const float* am = (const float*)d_in[1];
  const float* Wq = (const float*)d_in[2];
  const float* bq = (const float*)d_in[3];
  const float* Wk = (const float*)d_in[4];
  const float* bk = (const float*)d_in[5];
  const float* Wv = (const float*)d_in[6];
  const float* bv = (const float*)d_in[7];
  const float* Wo = (const float*)d_in[8];
  const float* bo = (const float*)d_in[9];
  float* out = (float*)d_out;

  const size_t XE  = (size_t)B_ * S_ * HID_;
  const size_t WQE = (size_t)HID_ * HID_;
  const size_t WKE = (size_t)KVD_ * HID_;
  const size_t QE  = (size_t)B_ * S_ * HID_;
  const size_t KE  = (size_t)B_ * S_ * KVD_;

  bf16* xb  = (bf16*)d_ws;
  bf16* wqb = xb + XE;
  bf16* wkb = wqb + WQE;
  bf16* wvb = wkb + WKE;
  bf16* wob = wvb + WKE;
  bf16* qbuf = wob + WQE;     // Q row-major [B*S, HID]
  bf16* kbuf = qbuf + QE;     // K row-major [B*S, KVD]
  bf16* vtbuf = kbuf + KE;    // V^T [B,KV,D,S]
  bf16* abuf = vtbuf + KE;    // attn out [B,S,HID]

  dim3 blk(256);
  CvtJob jx  = { x,  xb,  (int)(XE / 4) };
  CvtJob jwq = { Wq, wqb, (int)(WQE / 4) };
  CvtJob jwk = { Wk, wkb, (int)(WKE / 4) };
  CvtJob jwv = { Wv, wvb, (int)(WKE / 4) };
  CvtJob jwo = { Wo, wob, (int)(WQE / 4) };
  cvt_multi<<<dim3(512, 5), blk, 0, stream>>>(jx, jwq, jwk, jwv, jwo);

  const int M = B_ * S_;
  gemm_qkv<<<dim3(M / 128, 24), blk, 0, stream>>>(xb, wqb, wkb, wvb, bq, bk, bv,
                                                  qbuf, kbuf, vtbuf);
  attn_fwd<<<dim3(S_ / 256, B_ * H_), blk, 0, stream>>>(qbuf, kbuf, vtbuf, am, abuf);
  gemm_out<<<dim3(M / 128, HID_ / 128), blk, 0, stream>>>(abuf, wob, bo, out);
}